// Round 5
// baseline (16015.047 us; speedup 1.0000x reference)
//
#include <hip/hip_runtime.h>
#include <hip/hip_bf16.h>
#include <cstdint>
#include <cstddef>

// ---------------------------------------------------------------------------
// 3-layer LSTM (AWD-LSTM encoder, eval), S=512 B=64 V=50000 E=400 H=1150.
// FP32 in/out; fp16 MFMA compute with fp32 accumulation.
//
// r10: 512-thread blocks + register-batched loads. Evidence across r5-r9:
// step time tracks DEPENDENT-LOAD-CHAIN LENGTH, not bytes (r5->r6 removed
// in-loop streamed B loads: -18.5 us/step; r7 fence pushed L2 loads to MALL
// latency: +22.5; r9 removed 32 MB/step of bypass reads: only -2). At
// VGPR=64 (forced by 1024-thread blocks) the compiler serializes the ~50-70
// loads/wave/step. Now: 8 waves/block, __launch_bounds__(512,2) -> 256 VGPR
// ceiling; each wave owns TWO m-tiles (kq=w&3, mh=w>>2), so every B
// fragment is loaded once and feeds 2 MFMAs (streamed-B traffic halved),
// and all A+B fragments for a step fit in registers -> one batched issue +
// single drain instead of a serialized chain. MALL-latency loads (hseq)
// issue first, L2-hit loads after, MFMAs last.
// From r9: full-seq hseq buffers (virgin-address cached consumer reads, no
// fence needed; producers sc0sc1 write-through), L1 IH/HH split, 241
// blocks (72/72/72/25) co-resident, tree barrier, fragment-major LDS
// weights, shuffle-packed 16B h stores, sched_barrier(0) after asm waits.
// ---------------------------------------------------------------------------

typedef _Float16 f16x8 __attribute__((ext_vector_type(8)));
typedef float f32x4 __attribute__((ext_vector_type(4)));
typedef unsigned int u32x4 __attribute__((ext_vector_type(4)));

#define LSTM_NBLK   241
#define LSTM_WSTEPS 515
#define THREADS     512
#define LDS_W_HALFS (4 * 36 * 64 * 8)             // 73728 halves = 147456 B
#define LDS_TOTAL_BYTES (LDS_W_HALFS * 2 + 16384) // + 4x1024 fp32 gates = 163840
#define GO_BASE 248                               // go lines start at this slot

struct KParams {
  const unsigned short* res[3];   // resident W: Whh0, Whh1, Wih2 (frag-major, NKB=36)
  const unsigned short* strm[3];  // Wih0(13), Wih1(36), Whh2(13) frag-major
  const float* bias[3];           // bih+bhh fused [4][1152] fp32
  const unsigned short* xin0;     // gathered emb  [512][64][416] fp16 (immutable)
  unsigned short* hseq[3];        // full-seq h: [513][64][HSTR] fp16 (h_t at slot t+1)
  float* part;                    // L1 partial gates [2][72][1024][4] fp32
  float* out;                     // [512][64][400] fp32
  int* bar;                       // arrive[241] + go[8] flags, 128B-spaced
};

__device__ __forceinline__ float sigm_(float x) { return 1.0f / (1.0f + __expf(-x)); }
__device__ __forceinline__ float tanh_(float x) { return 2.0f * sigm_(2.0f * x) - 1.0f; }
__device__ __forceinline__ unsigned short f2h(float x) {
  _Float16 h = (_Float16)x;
  return __builtin_bit_cast(unsigned short, h);
}
// Device-coherent ops: bypass L1/L2, hit the coherence point (MALL).
__device__ __forceinline__ f32x4 load_sc128f(const float* p) {
  f32x4 r;
  asm volatile("global_load_dwordx4 %0, %1, off sc0 sc1"
               : "=v"(r) : "v"(p) : "memory");
  return r;
}
__device__ __forceinline__ void store_sc128(unsigned short* p, u32x4 v) {
  asm volatile("global_store_dwordx4 %0, %1, off sc0 sc1" :: "v"(p), "v"(v) : "memory");
}
__device__ __forceinline__ void store_sc128f(float* p, f32x4 v) {
  asm volatile("global_store_dwordx4 %0, %1, off sc0 sc1" :: "v"(p), "v"(v) : "memory");
}
__device__ __forceinline__ void store_sc_i(int* p, int v) {
  asm volatile("global_store_dword %0, %1, off sc0 sc1" :: "v"(p), "v"(v) : "memory");
}
__device__ __forceinline__ int load_sc_i(const int* p) {
  int v;
  asm volatile("global_load_dword %0, %1, off sc0 sc1\n\ts_waitcnt vmcnt(0)"
               : "=v"(v) : "v"(p) : "memory");
  __builtin_amdgcn_sched_barrier(0);
  return v;
}
__device__ __forceinline__ void wait_vm0() {
  asm volatile("s_waitcnt vmcnt(0)" ::: "memory");
  __builtin_amdgcn_sched_barrier(0);
}

// Contention-free tree barrier. Monotonic step counters; no atomics.
__device__ __forceinline__ void grid_barrier(int* bar, int bid, int tid, int tau1) {
  wait_vm0();        // this wave's sc-stores confirmed (asm ops invisible to compiler)
  __syncthreads();   // => ALL waves' stores confirmed
  if (bid == 0) {
    if (tid >= 1 && tid < LSTM_NBLK) {
      int guard = 0;
      while (load_sc_i(&bar[tid * 32]) < tau1 && ++guard < (1 << 20))
        __builtin_amdgcn_s_sleep(1);
    }
    __syncthreads();                       // all arrivals observed
    if (tid < 8) store_sc_i(&bar[(GO_BASE + tid) * 32], tau1);
  } else {
    if (tid == 0) {
      store_sc_i(&bar[bid * 32], tau1);    // arrive (own line, no contention)
      int guard = 0;
      while (load_sc_i(&bar[(GO_BASE + (bid & 7)) * 32]) < tau1 && ++guard < (1 << 20))
        __builtin_amdgcn_s_sleep(1);
    }
    __syncthreads();
  }
}

// Elementwise LSTM for one gate-buffer entry e; zeros the slots after read.
template<bool HASP>
__device__ __forceinline__ float lstm_ew(float* gates, int e, const float b4[4],
                                         const f32x4* pl, float& c_val) {
  float pg[4];
#pragma unroll
  for (int s2 = 0; s2 < 4; ++s2) {
    pg[s2] = gates[s2 * 1024 + e];
    gates[s2 * 1024 + e] = 0.0f;
  }
  float ig = sigm_(pg[0] + (HASP ? (*pl)[0] : 0.0f) + b4[0]);
  float fg = sigm_(pg[1] + (HASP ? (*pl)[1] : 0.0f) + b4[1]);
  float gg = tanh_(pg[2] + (HASP ? (*pl)[2] : 0.0f) + b4[2]);
  float og = sigm_(pg[3] + (HASP ? (*pl)[3] : 0.0f) + b4[3]);
  c_val = fg * c_val + ig * gg;
  return og * tanh_(c_val);
}

// Wave-shuffle pack 16 halves of one row -> one 16B sc-store (lane&7==0).
__device__ __forceinline__ void pack_store16(unsigned short* base, int lane, float h) {
  unsigned v0  = (unsigned)f2h(h);
  unsigned o1  = __shfl_down(v0, 1);
  unsigned p01 = v0 | (o1 << 16);
  unsigned o2  = __shfl_down(p01, 2);
  unsigned o4a = __shfl_down(p01, 4);
  unsigned o4b = __shfl_down(o2, 4);
  if ((lane & 7) == 0) {
    u32x4 pk; pk[0] = p01; pk[1] = o2; pk[2] = o4a; pk[3] = o4b;
    store_sc128(base, pk);
  }
}

// ---------------- L0 (lag 0): Whh0 LDS-resident, Wih0 streamed -------------
__device__ __forceinline__ void run_l0(const KParams& p, int g, int bid,
                                       unsigned short* ldsW, float* gates) {
  const unsigned short* __restrict__ strmA = p.strm[0] + (size_t)g * (4 * 13 * 512);
  const unsigned short* __restrict__ xin   = p.xin0;
  unsigned short* __restrict__ own         = p.hseq[0];

  const int tid  = threadIdx.x;
  const int lane = tid & 63;
  const int w    = tid >> 6;        // 8 waves
  const int kq   = w & 3;
  const int m0   = (w >> 2) * 32;   // two m-tiles: m0, m0+16
  const int r    = lane & 15;
  const int q    = lane >> 4;

  {  // stage Whh0 fragments; zero gate buffer
    const uint4* src = (const uint4*)(p.res[0] + (size_t)g * LDS_W_HALFS);
    uint4* dst = (uint4*)ldsW;
    for (int i = tid; i < LDS_W_HALFS / 8; i += THREADS) dst[i] = src[i];
#pragma unroll
    for (int s2 = 0; s2 < 4; ++s2) {
      gates[s2 * 1024 + tid] = 0.0f;
      gates[s2 * 1024 + tid + 512] = 0.0f;
    }
  }
  const int jp = tid & 15;
  const int jglob = g * 16 + jp;
  float bias4[4];
#pragma unroll
  for (int ss = 0; ss < 4; ++ss) bias4[ss] = p.bias[0][ss * 1152 + jglob];
  float c0 = 0.0f, c1 = 0.0f;
  __syncthreads();

  for (int tau = 0; tau < LSTM_WSTEPS; ++tau) {
    const int t = tau;
    if (t < 512) {
      // ---- batch-issue h0_{t-1} loads first (deepest latency) ----
      f16x8 a2r[2][9];
#pragma unroll
      for (int mi = 0; mi < 2; ++mi) {
        const unsigned short* a2b =
            own + (size_t)t * (64 * 1152) + (size_t)(m0 + mi * 16 + r) * 1152 + q * 8;
#pragma unroll
        for (int i = 0; i < 9; ++i) a2r[mi][i] = *(const f16x8*)(a2b + (kq + 4 * i) * 32);
      }
      // ---- batch-issue x0 and Wih0 (L2-hot) ----
      f16x8 a1r[2][4]; f16x8 bS[4][4];
#pragma unroll
      for (int mi = 0; mi < 2; ++mi) {
        const unsigned short* a1b =
            xin + ((size_t)t * 64 + (m0 + mi * 16 + r)) * 416 + q * 8;
#pragma unroll
        for (int i = 0; i < 4; ++i) {
          int kb = kq + 4 * i;
          if (kb < 13) a1r[mi][i] = *(const f16x8*)(a1b + kb * 32);
        }
      }
#pragma unroll
      for (int i = 0; i < 4; ++i) {
        int kb = kq + 4 * i;
        if (kb < 13) {
#pragma unroll
          for (int s2 = 0; s2 < 4; ++s2)
            bS[i][s2] = *(const f16x8*)&strmA[((size_t)(s2 * 13 + kb) * 64 + lane) * 8];
        }
      }

      f32x4 acc[2][4];
#pragma unroll
      for (int mi = 0; mi < 2; ++mi)
#pragma unroll
        for (int s2 = 0; s2 < 4; ++s2) acc[mi][s2] = (f32x4){0, 0, 0, 0};

      // ---- phase 1: x_t @ Wih0^T (streamed B, shared across 2 m-tiles) ----
#pragma unroll
      for (int i = 0; i < 4; ++i) {
        int kb = kq + 4 * i;
        if (kb < 13) {
#pragma unroll
          for (int s2 = 0; s2 < 4; ++s2)
#pragma unroll
            for (int mi = 0; mi < 2; ++mi)
              acc[mi][s2] = __builtin_amdgcn_mfma_f32_16x16x32_f16(
                  a1r[mi][i], bS[i][s2], acc[mi][s2], 0, 0, 0);
        }
      }
      // ---- phase 2: h_{t-1} @ Whh0^T (LDS B) ----
#pragma unroll
      for (int i = 0; i < 9; ++i) {
        int kb = kq + 4 * i;
#pragma unroll
        for (int s2 = 0; s2 < 4; ++s2) {
          f16x8 b = *(const f16x8*)&ldsW[((s2 * 36 + kb) * 64 + lane) * 8];
#pragma unroll
          for (int mi = 0; mi < 2; ++mi)
            acc[mi][s2] = __builtin_amdgcn_mfma_f32_16x16x32_f16(
                a2r[mi][i], b, acc[mi][s2], 0, 0, 0);
        }
      }
      // ---- reduce across the 4 kq-waves via LDS atomics ----
#pragma unroll
      for (int mi = 0; mi < 2; ++mi)
#pragma unroll
        for (int s2 = 0; s2 < 4; ++s2)
#pragma unroll
          for (int i = 0; i < 4; ++i)
            atomicAdd(&gates[s2 * 1024 + (m0 + mi * 16 + q * 4 + i) * 16 + r],
                      acc[mi][s2][i]);
      __syncthreads();

      float h0 = lstm_ew<false>(gates, tid, bias4, nullptr, c0);
      float h1 = lstm_ew<false>(gates, tid + 512, bias4, nullptr, c1);
      if (jglob >= 1150) { h0 = 0.0f; h1 = 0.0f; }
      const int b0 = tid >> 4, b1 = b0 + 32;
      pack_store16(own + ((size_t)(t + 1) * 64 + b0) * 1152 + jglob, lane, h0);
      pack_store16(own + ((size_t)(t + 1) * 64 + b1) * 1152 + jglob, lane, h1);
    }
    grid_barrier(p.bar, bid, tid, tau + 1);
  }
}

// ---------------- L1 input half: partial = x_t @ Wih1^T (lag 1) ------------
__device__ __forceinline__ void run_l1_ih(const KParams& p, int g, int bid,
                                          unsigned short* ldsW, float* gates) {
  const unsigned short* __restrict__ xin = p.hseq[0];
  const int tid  = threadIdx.x;
  const int lane = tid & 63;
  const int w    = tid >> 6;
  const int kq   = w & 3;
  const int m0   = (w >> 2) * 32;
  const int r    = lane & 15;
  const int q    = lane >> 4;

  {  // stage Wih1 fragments (strm1 layout == res layout, NKB=36)
    const uint4* src = (const uint4*)(p.strm[1] + (size_t)g * LDS_W_HALFS);
    uint4* dst = (uint4*)ldsW;
    for (int i = tid; i < LDS_W_HALFS / 8; i += THREADS) dst[i] = src[i];
#pragma unroll
    for (int s2 = 0; s2 < 4; ++s2) {
      gates[s2 * 1024 + tid] = 0.0f;
      gates[s2 * 1024 + tid + 512] = 0.0f;
    }
  }
  __syncthreads();

  for (int tau = 0; tau < LSTM_WSTEPS; ++tau) {
    const int t = tau - 1;
    if (t >= 0 && t < 512) {
      // x1_t = h0_t at hseq0 slot t+1 (virgin-fresh cached)
      f16x8 a1r[2][9];
#pragma unroll
      for (int mi = 0; mi < 2; ++mi) {
        const unsigned short* a1b =
            xin + (size_t)(t + 1) * (64 * 1152) + (size_t)(m0 + mi * 16 + r) * 1152 + q * 8;
#pragma unroll
        for (int i = 0; i < 9; ++i) a1r[mi][i] = *(const f16x8*)(a1b + (kq + 4 * i) * 32);
      }
      f32x4 acc[2][4];
#pragma unroll
      for (int mi = 0; mi < 2; ++mi)
#pragma unroll
        for (int s2 = 0; s2 < 4; ++s2) acc[mi][s2] = (f32x4){0, 0, 0, 0};
#pragma unroll
      for (int i = 0; i < 9; ++i) {
        int kb = kq + 4 * i;
#pragma unroll
        for (int s2 = 0; s2 < 4; ++s2) {
          f16x8 b = *(const f16x8*)&ldsW[((s2 * 36 + kb) * 64 + lane) * 8];
#pragma unroll
          for (int mi = 0; mi < 2; ++mi)
            acc[mi][s2] = __builtin_amdgcn_mfma_f32_16x16x32_f16(
                a1r[mi][i], b, acc[mi][s2], 0, 0, 0);
        }
      }
#pragma unroll
      for (int mi = 0; mi < 2; ++mi)
#pragma unroll
        for (int s2 = 0; s2 < 4; ++s2)
#pragma unroll
          for (int i = 0; i < 4; ++i)
            atomicAdd(&gates[s2 * 1024 + (m0 + mi * 16 + q * 4 + i) * 16 + r],
                      acc[mi][s2][i]);
      __syncthreads();

      f32x4 pk0, pk1;
#pragma unroll
      for (int s2 = 0; s2 < 4; ++s2) {
        pk0[s2] = gates[s2 * 1024 + tid];       gates[s2 * 1024 + tid] = 0.0f;
        pk1[s2] = gates[s2 * 1024 + tid + 512]; gates[s2 * 1024 + tid + 512] = 0.0f;
      }
      float* pb = p.part + (size_t)((t & 1) * 72 + g) * 1024 * 4;
      store_sc128f(pb + (size_t)tid * 4, pk0);
      store_sc128f(pb + (size_t)(tid + 512) * 4, pk1);
    }
    grid_barrier(p.bar, bid, tid, tau + 1);
  }
}

// ---------------- L1 recurrent half: gates/elementwise/h (lag 2) -----------
__device__ __forceinline__ void run_l1_hh(const KParams& p, int g, int bid,
                                          unsigned short* ldsW, float* gates) {
  unsigned short* __restrict__ own = p.hseq[1];
  const int tid  = threadIdx.x;
  const int lane = tid & 63;
  const int w    = tid >> 6;
  const int kq   = w & 3;
  const int m0   = (w >> 2) * 32;
  const int r    = lane & 15;
  const int q    = lane >> 4;

  {  // stage Whh1 fragments
    const uint4* src = (const uint4*)(p.res[1] + (size_t)g * LDS_W_HALFS);
    uint4* dst = (uint4*)ldsW;
    for (int i = tid; i < LDS_W_HALFS / 8; i += THREADS) dst[i] = src[i];
#pragma unroll
    for (int s2 = 0; s2 < 4; ++s2) {
      gates[s2 * 1024 + tid] = 0.0f;
      gates[s2 * 1024 + tid + 512] = 0.0f;
    }
  }
  const int jp = tid & 15;
  const int jglob = g * 16 + jp;
  float bias4[4];
#pragma unroll
  for (int ss = 0; ss < 4; ++ss) bias4[ss] = p.bias[1][ss * 1152 + jglob];
  float c0 = 0.0f, c1 = 0.0f;
  __syncthreads();

  for (int tau = 0; tau < LSTM_WSTEPS; ++tau) {
    const int t = tau - 2;
    if (t >= 0 && t < 512) {
      // h1_{t-1} at slot t (virgin-fresh cached)
      f16x8 a2r[2][9];
#pragma unroll
      for (int mi = 0; mi < 2; ++mi) {
        const unsigned short* a2b =
            own + (size_t)t * (64 * 1152) + (size_t)(m0 + mi * 16 + r) * 1152 + q * 8;
#pragma unroll
        for (int i = 0; i < 9; ++i) a2r[mi][i] = *(const f16x8*)(a2b + (kq + 4 * i) * 32);
      }
      // IH partial (parity-2 address reuse => sc bypass path)
      const float* pb = p.part + (size_t)((t & 1) * 72 + g) * 1024 * 4;
      f32x4 pl0 = load_sc128f(pb + (size_t)tid * 4);
      f32x4 pl1 = load_sc128f(pb + (size_t)(tid + 512) * 4);
      wait_vm0();

      f32x4 acc[2][4];
#pragma unroll
      for (int mi = 0; mi < 2; ++mi)
#pragma unroll
        for (int s2 = 0; s2 < 4; ++s2) acc[mi][s2] = (f32x4){0, 0, 0, 0};
#pragma unroll
      for (int i = 0; i < 9; ++i) {
        int kb = kq + 4 * i;
#pragma unroll
        for (int s2 = 0; s2 < 4; ++s2) {
          f16x8 b = *(const f16x8*)&ldsW[((s2 * 36 + kb) * 64 + lane) * 8];
#pragma unroll
          for (int mi = 0; mi < 2; ++mi)
            acc[mi][s2] = __builtin_amdgcn_mfma_f32_16x16x32_f16(
                a2r[mi][i], b, acc[mi][s2], 0, 0, 0);
        }
      }
#pragma unroll
      for (int mi = 0; mi < 2; ++mi)
#pragma unroll
        for (int s2 = 0; s2 < 4; ++s2)
#pragma unroll
          for (int i = 0; i < 4; ++i)
            atomicAdd(&gates[s2 * 1024 + (m0 + mi * 16 + q * 4 + i) * 16 + r],
                      acc[mi][s2][i]);
      __syncthreads();

      float h0 = lstm_ew<true>(gates, tid, bias4, &pl0, c0);
      float h1 = lstm_ew<true>(gates, tid + 512, bias4, &pl1, c1);
      if (jglob >= 1150) { h0 = 0.0f; h1 = 0.0f; }
      const int b0 = tid >> 4, b1 = b0 + 32;
      pack_store16(own + ((size_t)(t + 1) * 64 + b0) * 1152 + jglob, lane, h0);
      pack_store16(own + ((size_t)(t + 1) * 64 + b1) * 1152 + jglob, lane, h1);
    }
    grid_barrier(p.bar, bid, tid, tau + 1);
  }
}

// ---------------- L2 (lag 3): Wih2 LDS-resident, Whh2 streamed -------------
__device__ __forceinline__ void run_l2(const KParams& p, int g, int bid,
                                       unsigned short* ldsW, float* gates) {
  const unsigned short* __restrict__ strmB = p.strm[2] + (size_t)g * (4 * 13 * 512);
  const unsigned short* __restrict__ xin   = p.hseq[1];
  unsigned short* __restrict__ own         = p.hseq[2];

  const int tid  = threadIdx.x;
  const int lane = tid & 63;
  const int w    = tid >> 6;
  const int kq   = w & 3;
  const int m0   = (w >> 2) * 32;
  const int r    = lane & 15;
  const int q    = lane >> 4;

  {  // stage Wih2 fragments
    const uint4* src = (const uint4*)(p.res[2] + (size_t)g * LDS_W_HALFS);
    uint4* dst = (uint4*)ldsW;
    for (int i = tid; i < LDS_W_HALFS / 8; i += THREADS) dst[i] = src[i];
#pragma unroll
    for (int s2 = 0; s2 < 4; ++s2) {
      gates[s2 * 1024 + tid] = 0.0f;
      gates[s2 * 1024 + tid + 512] = 0.0f;
    }
  }
  const int jp = tid & 15;
  const int jglob = g * 16 + jp;
  float bias4[4];
#pragma unroll
  for (int ss = 0; ss < 4; ++ss) bias4[ss] = p.bias[2][ss * 1152 + jglob];
  float c0 = 0.0f, c1 = 0.0f;
  __syncthreads();

  for (int tau = 0; tau < LSTM_WSTEPS; ++tau) {
    const int t = tau - 3;
    if (t >= 0 && t < 512) {
      // h1_t at hseq1 slot t+1 (MALL-deep) — issue first
      f16x8 a1r[2][9];
#pragma unroll
      for (int mi = 0; mi < 2; ++mi) {
        const unsigned short* a1b =
            xin + (size_t)(t + 1) * (64 * 1152) + (size_t)(m0 + mi * 16 + r) * 1152 + q * 8;
#pragma unroll
        for (int i = 0; i < 9; ++i) a1r[mi][i] = *(const f16x8*)(a1b + (kq + 4 * i) * 32);
      }
      // h2_{t-1} at hseq2 slot t
      f16x8 a2r[2][4];
#pragma unroll
      for (int mi = 0; mi < 2; ++mi) {
        const unsigned short* a2b =
            own + (size_t)t * (64 * 416) + (size_t)(m0 + mi * 16 + r) * 416 + q * 8;
#pragma unroll
        for (int i = 0; i < 4; ++i) {
          int kb = kq + 4 * i;
          if (kb < 13) a2r[mi][i] = *(const f16x8*)(a2b + kb * 32);
        }
      }
      // Whh2 streamed (L2-hot)
      f16x8 bS[4][4];
#pragma unroll
      for (int i = 0; i < 4; ++i) {
        int kb = kq + 4 * i;
        if (kb < 13) {
#pragma unroll
          for (int s2 = 0; s2 < 4; ++s2)
            bS[i][s2] = *(const f16x8*)&strmB[((size_t)(s2 * 13 + kb) * 64 + lane) * 8];
        }
      }

      f32x4 acc[2][4];
#pragma unroll
      for (int mi = 0; mi < 2; ++mi)
#pragma unroll
        for (int s2 = 0; s2 < 4; ++s2) acc[mi][s2] = (f32x4){0, 0, 0, 0};

      // phase 1: h1_t @ Wih2^T (LDS B)
#pragma unroll
      for (int i = 0; i < 9; ++i) {
        int kb = kq + 4 * i;
#pragma unroll
        for (int s2 = 0; s2 < 4; ++s2) {
          f16x8 b = *(const f16x8*)&ldsW[((s2 * 36 + kb) * 64 + lane) * 8];
#pragma unroll
          for (int mi = 0; mi < 2; ++mi)
            acc[mi][s2] = __builtin_amdgcn_mfma_f32_16x16x32_f16(
                a1r[mi][i], b, acc[mi][s2], 0, 0, 0);
        }
      }
      // phase 2: h2_{t-1} @ Whh2^T (streamed B)
#pragma unroll
      for (int i = 0; i < 4; ++i) {
        int kb = kq + 4 * i;
        if (kb < 13) {
#pragma unroll
          for (int s2 = 0; s2 < 4; ++s2)
#pragma unroll
            for (int mi = 0; mi < 2; ++mi)
              acc[mi][s2] = __builtin_amdgcn_mfma_f32_16x16x32_f16(
                  a2r[mi][i], bS[i][s2], acc[mi][s2], 0, 0, 0);
        }
      }
#pragma unroll
      for (int mi = 0; mi < 2; ++mi)
#pragma unroll
        for (int s2 = 0; s2 < 4; ++s2)
#pragma unroll
          for (int i = 0; i < 4; ++i)
            atomicAdd(&gates[s2 * 1024 + (m0 + mi * 16 + q * 4 + i) * 16 + r],
                      acc[mi][s2][i]);
      __syncthreads();

      float h0 = lstm_ew<false>(gates, tid, bias4, nullptr, c0);
      float h1 = lstm_ew<false>(gates, tid + 512, bias4, nullptr, c1);
      if (jglob >= 400) { h0 = 0.0f; h1 = 0.0f; }
      const int b0 = tid >> 4, b1 = b0 + 32;
      pack_store16(own + ((size_t)(t + 1) * 64 + b0) * 416 + jglob, lane, h0);
      pack_store16(own + ((size_t)(t + 1) * 64 + b1) * 416 + jglob, lane, h1);
      if (jglob < 400) {
        p.out[((size_t)t * 64 + b0) * 400 + jglob] = h0;
        p.out[((size_t)t * 64 + b1) * 400 + jglob] = h1;
      }
    }
    grid_barrier(p.bar, bid, tid, tau + 1);
  }
}

__global__ void __launch_bounds__(THREADS, 2) lstm_persistent(KParams p) {
  extern __shared__ unsigned short smem[];
  unsigned short* ldsW = smem;
  float* gates = (float*)(smem + LDS_W_HALFS);
  const int bid = blockIdx.x;
  if (bid < 72)       run_l0(p, bid, bid, ldsW, gates);
  else if (bid < 144) run_l1_ih(p, bid - 72, bid, ldsW, gates);
  else if (bid < 216) run_l1_hh(p, bid - 144, bid, ldsW, gates);
  else                run_l2(p, bid - 216, bid, ldsW, gates);
}

// --- prep: fp32 [4*Jext][K] -> fp16 fragment-major [g][(s*NKB+kb)*64+lane][8] ---
__global__ void prep_weights(const float* __restrict__ src,
                             unsigned short* __restrict__ dst,
                             int Jext, int jg, int K, int NKB) {
  const int n = jg * 4 * NKB * 512;
  for (int idx = blockIdx.x * blockDim.x + threadIdx.x; idx < n;
       idx += gridDim.x * blockDim.x) {
    int e = idx & 7;
    int t2 = idx >> 3;
    int ln = t2 & 63; t2 >>= 6;
    int kb = t2 % NKB; t2 /= NKB;
    int s = t2 & 3;
    int g = t2 >> 2;
    int j = g * 16 + (ln & 15);
    int k = kb * 32 + (ln >> 4) * 8 + e;
    unsigned short v = 0;
    if (j < Jext && k < K) v = f2h(src[(size_t)(s * Jext + j) * K + k]);
    dst[idx] = v;
  }
}

__global__ void prep_bias(const float* __restrict__ bih,
                          const float* __restrict__ bhh,
                          float* __restrict__ dst, int Dh) {
  const int n = 4 * 1152;
  for (int idx = blockIdx.x * blockDim.x + threadIdx.x; idx < n;
       idx += gridDim.x * blockDim.x) {
    int s = idx / 1152, j = idx % 1152;
    float v = 0.0f;
    if (j < Dh) v = bih[s * Dh + j] + bhh[s * Dh + j];
    dst[idx] = v;
  }
}

// gather emb[tokens] (fp32) into padded fp16 [512*64][416] (cols 400..415 = 0)
__global__ void prep_gather(const int* __restrict__ tokens,
                            const float* __restrict__ emb,
                            unsigned short* __restrict__ xin0) {
  const int n = 512 * 64 * 52;
  for (int idx = blockIdx.x * blockDim.x + threadIdx.x; idx < n;
       idx += gridDim.x * blockDim.x) {
    int row = idx / 52;
    int cp  = idx - row * 52;
    unsigned short v[8] = {0, 0, 0, 0, 0, 0, 0, 0};
    if (cp < 50) {
      const float* src = emb + (size_t)tokens[row] * 400 + cp * 8;
      float4 a = *(const float4*)(src);
      float4 b = *(const float4*)(src + 4);
      v[0] = f2h(a.x); v[1] = f2h(a.y); v[2] = f2h(a.z); v[3] = f2h(a.w);
      v[4] = f2h(b.x); v[5] = f2h(b.y); v[6] = f2h(b.z); v[7] = f2h(b.w);
    }
    *(uint4*)(xin0 + (size_t)row * 416 + cp * 8) = *(const uint4*)v;
  }
}

extern "C" void kernel_launch(void* const* d_in, const int* in_sizes, int n_in,
                              void* d_out, int out_size, void* d_ws, size_t ws_size,
                              hipStream_t stream) {
  const int*   tokens = (const int*)d_in[0];
  const float* emb  = (const float*)d_in[1];
  const float* Wih0 = (const float*)d_in[2];
  const float* Whh0 = (const float*)d_in[3];
  const float* bih0 = (const float*)d_in[4];
  const float* bhh0 = (const float*)d_in[5];
  const float* Wih1 = (const float*)d_in[8];
  const float* Whh1 = (const float*)d_in[9];
  const float* bih1 = (const float*)d_in[10];
  const float* bhh1 = (const float*)d_in[11];
  const float* Wih2 = (const float*)d_in[14];
  const float* Whh2 = (const float*)d_in[15];
  const float* bih2 = (const float*)d_in[16];
  const float* bhh2 = (const float*)d_in[17];

  char* ws = (char*)d_ws;
  size_t off = 0;
  auto alloc = [&](size_t bytes) -> char* {
    char* ptr = ws + off;
    off += (bytes + 255) & ~(size_t)255;
    return ptr;
  };
  unsigned short* res0  = (unsigned short*)alloc(72ull * 4 * 36 * 512 * 2);
  unsigned short* res1  = (unsigned short*)alloc(72ull * 4 * 36 * 512 * 2);
  unsigned short* res2  = (unsigned short*)alloc(25ull * 4 * 36 * 512 * 2);
  unsigned short* strm0 = (unsigned short*)alloc(72ull * 4 * 13 * 512 * 2);
  unsigned short* strm1 = (unsigned short*)alloc(72ull * 4 * 36 * 512 * 2);
  unsigned short* strm2 = (unsigned short*)alloc(25ull * 4 * 13 * 512 * 2);
  float* bias0 = (float*)alloc(4ull * 1152 * 4);
  float* bias1 = (float*)alloc(4ull * 1152 * 4);
  float* bias2 = (float*)alloc(4ull * 1152 * 4);
  unsigned short* xin0  = (unsigned short*)alloc(512ull * 64 * 416 * 2);
  unsigned short* hseq0 = (unsigned short*)alloc(513ull * 64 * 1152 * 2); // 75.6 MB
  unsigned short* hseq1 = (unsigned short*)alloc(513ull * 64 * 1152 * 2); // 75.6 MB
  unsigned short* hseq2 = (unsigned short*)alloc(513ull * 64 * 416 * 2);  // 27.3 MB
  float* part = (float*)alloc(2ull * 72 * 1024 * 4 * 4);        // 2.36 MB
  int* bar = (int*)alloc((GO_BASE + 8) * 32 * 4);   // arrive[241]+go[8], 128B lines
  if (off > ws_size) return;

  hipLaunchKernelGGL(prep_gather, dim3(2048), dim3(256), 0, stream, tokens, emb, xin0);
  hipLaunchKernelGGL(prep_weights, dim3(4096), dim3(256), 0, stream, Whh0, res0, 1150, 72, 1150, 36);
  hipLaunchKernelGGL(prep_weights, dim3(4096), dim3(256), 0, stream, Whh1, res1, 1150, 72, 1150, 36);
  hipLaunchKernelGGL(prep_weights, dim3(4096), dim3(256), 0, stream, Wih2, res2, 400, 25, 1150, 36);
  hipLaunchKernelGGL(prep_weights, dim3(4096), dim3(256), 0, stream, Wih0, strm0, 1150, 72, 400, 13);
  hipLaunchKernelGGL(prep_weights, dim3(4096), dim3(256), 0, stream, Wih1, strm1, 1150, 72, 1150, 36);
  hipLaunchKernelGGL(prep_weights, dim3(4096), dim3(256), 0, stream, Whh2, strm2, 400, 25, 400, 13);
  hipLaunchKernelGGL(prep_bias, dim3(8), dim3(256), 0, stream, bih0, bhh0, bias0, 1150);
  hipLaunchKernelGGL(prep_bias, dim3(8), dim3(256), 0, stream, bih1, bhh1, bias1, 1150);
  hipLaunchKernelGGL(prep_bias, dim3(8), dim3(256), 0, stream, bih2, bhh2, bias2, 400);
  // Only slot 0 (h_{-1} = 0) needs zeroing; all other slots are write-before-read.
  (void)hipMemsetAsync(hseq0, 0, 64ull * 1152 * 2, stream);
  (void)hipMemsetAsync(hseq1, 0, 64ull * 1152 * 2, stream);
  (void)hipMemsetAsync(hseq2, 0, 64ull * 416 * 2, stream);
  (void)hipMemsetAsync(bar, 0, (GO_BASE + 8) * 32 * 4, stream);

  KParams kp;
  kp.res[0] = res0;  kp.res[1] = res1;  kp.res[2] = res2;
  kp.strm[0] = strm0; kp.strm[1] = strm1; kp.strm[2] = strm2;
  kp.bias[0] = bias0; kp.bias[1] = bias1; kp.bias[2] = bias2;
  kp.xin0 = xin0;
  kp.hseq[0] = hseq0; kp.hseq[1] = hseq1; kp.hseq[2] = hseq2;
  kp.part = part;
  kp.out = (float*)d_out;
  kp.bar = bar;

  (void)hipFuncSetAttribute((const void*)lstm_persistent,
                            hipFuncAttributeMaxDynamicSharedMemorySize,
                            LDS_TOTAL_BYTES);
  hipLaunchKernelGGL(lstm_persistent, dim3(LSTM_NBLK), dim3(THREADS),
                     LDS_TOTAL_BYTES, stream, kp);
}